// Round 3
// baseline (204.204 us; speedup 1.0000x reference)
//
#include <hip/hip_runtime.h>

#define DF 128
#define SCAN_B 64
#define SCAN_T 256
#define GN 16           // nodes per gather/gemm block

typedef __attribute__((ext_vector_type(8))) short short8;
typedef __attribute__((ext_vector_type(4))) float float4v;

__device__ __forceinline__ unsigned int bf16rne(float f) {
    unsigned int u = __float_as_uint(f);
    return (u + 0x7fffu + ((u >> 16) & 1u)) >> 16;
}
__device__ __forceinline__ float bf16lo(unsigned int w) {
    return __uint_as_float(w << 16);
}
__device__ __forceinline__ float bf16hi(unsigned int w) {
    return __uint_as_float(w & 0xffff0000u);
}

// ---------------------------------------------------------------------------
// prep: fused (a) histogram of dst, (b) x fp32->bf16 cast into compact xb,
// (c) [Wl;Wr] swizzle into MFMA B-fragment order (bf16).
// ---------------------------------------------------------------------------
__global__ __launch_bounds__(256) void sage_prep(
    const float* __restrict__ x, const int* __restrict__ dst,
    const float* __restrict__ Wl, const float* __restrict__ Wr,
    int* __restrict__ cnt, char* __restrict__ xb, uint4* __restrict__ Bf,
    int N, int E)
{
    int tid = blockIdx.x * 256 + threadIdx.x;

    if (tid < N * 16) {                      // xcast: 16 threads/row
        int n = tid >> 4;
        int c = (tid & 15) * 8;
        const float4* xp = (const float4*)&x[(size_t)n * DF + c];
        float4 a = xp[0], b = xp[1];
        uint4 o;
        o.x = bf16rne(a.x) | (bf16rne(a.y) << 16);
        o.y = bf16rne(a.z) | (bf16rne(a.w) << 16);
        o.z = bf16rne(b.x) | (bf16rne(b.y) << 16);
        o.w = bf16rne(b.z) | (bf16rne(b.w) << 16);
        *(uint4*)(xb + (size_t)n * 256 + (size_t)(tid & 15) * 16) = o;
    }

    if (tid < E) atomicAdd(&cnt[dst[tid]], 1);   // histogram

    if (tid < 4096) {                        // bprep
        int lane = tid & 63;
        int ctks = tid >> 6;
        int ks = ctks >> 3, ct = ctks & 7;
        int q = lane >> 4, m16 = lane & 15;
        int n = ct * 16 + m16;
        unsigned int w[4];
        #pragma unroll
        for (int p = 0; p < 4; ++p) {
            int k0 = ks * 32 + q * 8 + p * 2;
            float f0 = (k0 < DF) ? Wl[k0 * DF + n] : Wr[(k0 - DF) * DF + n];
            float f1 = (k0 + 1 < DF) ? Wl[(k0 + 1) * DF + n] : Wr[(k0 + 1 - DF) * DF + n];
            w[p] = bf16rne(f0) | (bf16rne(f1) << 16);
        }
        uint4 o = {w[0], w[1], w[2], w[3]};
        Bf[tid] = o;
    }
}

// ---------------------------------------------------------------------------
// scan pass 1: per-block reduce -> blktot
// ---------------------------------------------------------------------------
__global__ __launch_bounds__(SCAN_T) void scan_reduce(
    const int* __restrict__ cnt, int* __restrict__ blktot, int N)
{
    __shared__ int sdata[SCAN_T];
    const int t = threadIdx.x, b = blockIdx.x;
    const int chunk = (N + SCAN_B * SCAN_T - 1) / (SCAN_B * SCAN_T);
    const int lo = (b * SCAN_T + t) * chunk;
    const int hi = min(lo + chunk, N);
    int total = 0;
    for (int i = lo; i < hi; ++i) total += cnt[i];
    sdata[t] = total;
    __syncthreads();
    for (int s = SCAN_T / 2; s > 0; s >>= 1) {
        if (t < s) sdata[t] += sdata[t + s];
        __syncthreads();
    }
    if (t == 0) blktot[b] = sdata[0];
}

// ---------------------------------------------------------------------------
// scan pass 2: block base via 64 parallel loads + LDS scan + write
// ---------------------------------------------------------------------------
__global__ __launch_bounds__(SCAN_T) void scan_write(
    int* __restrict__ off, int* __restrict__ cur,
    const int* __restrict__ blktot, int N, int E)
{
    __shared__ int sdata[SCAN_T];
    __shared__ int sbl[64];
    __shared__ int sbase;
    const int t = threadIdx.x, b = blockIdx.x;
    const int chunk = (N + SCAN_B * SCAN_T - 1) / (SCAN_B * SCAN_T);
    const int lo = (b * SCAN_T + t) * chunk;
    const int hi = min(lo + chunk, N);

    if (t < 64) sbl[t] = (t < b) ? blktot[t] : 0;
    int total = 0;
    for (int i = lo; i < hi; ++i) total += off[i];
    sdata[t] = total;
    __syncthreads();
    if (t == 0) {
        int s = 0;
        #pragma unroll
        for (int i = 0; i < 64; ++i) s += sbl[i];
        sbase = s;
    }
    for (int s = 1; s < SCAN_T; s <<= 1) {
        int v = (t >= s) ? sdata[t - s] : 0;
        __syncthreads();
        sdata[t] += v;
        __syncthreads();
    }
    int running = sbase + ((t > 0) ? sdata[t - 1] : 0);
    for (int i = lo; i < hi; ++i) {
        int c = off[i];
        off[i] = running;
        cur[i] = running;
        running += c;
    }
    if (b == 0 && t == 0) off[N] = E;
}

// ---------------------------------------------------------------------------
// counting-sort of src by dst bucket
// ---------------------------------------------------------------------------
__global__ __launch_bounds__(256) void sage_sort(
    const int* __restrict__ src, const int* __restrict__ dst,
    int* __restrict__ cur, int* __restrict__ srt, int E)
{
    int e = blockIdx.x * 256 + threadIdx.x;
    if (e < E) {
        int p = atomicAdd(&cur[dst[e]], 1);
        srt[p] = src[e];
    }
}

// ---------------------------------------------------------------------------
// gather: barrier-free, LDS-free. 16-lane group owns one node; one coalesced
// srt load per 16 edges (shfl-broadcast); up to 16 gather loads in flight
// before unpack; next index batch prefetched under current unpack.
// Writes bf16 mean row to mb.
// ---------------------------------------------------------------------------
#define UNPACK(vv) { \
    a0 += bf16lo((vv).x); a1 += bf16hi((vv).x); \
    a2 += bf16lo((vv).y); a3 += bf16hi((vv).y); \
    a4 += bf16lo((vv).z); a5 += bf16hi((vv).z); \
    a6 += bf16lo((vv).w); a7 += bf16hi((vv).w); }

__global__ __launch_bounds__(256, 5) void sage_gath(
    const char* __restrict__ xb, const int* __restrict__ off,
    const int* __restrict__ srt, char* __restrict__ mb, int N)
{
    const int t = threadIdx.x;
    const int ln = t & 15;
    const int n = blockIdx.x * GN + (t >> 4);
    if (n >= N) return;
    const size_t lnb = (size_t)ln * 16;

    const int start = off[n];
    const int end   = off[n + 1];
    const int deg = max(end - start, 1);

    float a0 = 0.f, a1 = 0.f, a2 = 0.f, a3 = 0.f;
    float a4 = 0.f, a5 = 0.f, a6 = 0.f, a7 = 0.f;

    int sv = 0;
    if (start + ln < end) sv = srt[start + ln];

    for (int e0 = start; e0 < end; e0 += 16) {
        int svn = 0;
        if (e0 + 16 + ln < end) svn = srt[e0 + 16 + ln];
        const int m = end - e0;              // group-uniform; may exceed 16

        uint4 v[16];
        #pragma unroll
        for (int j = 0; j < 16; ++j) {
            if (j < m) {
                int s = __shfl(sv, j, 16);
                v[j] = *(const uint4*)(xb + (size_t)s * 256 + lnb);
            }
        }
        #pragma unroll
        for (int j = 0; j < 16; ++j) {
            if (j < m) UNPACK(v[j]);
        }
        sv = svn;
    }

    float inv = 1.0f / (float)deg;
    uint4 o;
    o.x = bf16rne(a0 * inv) | (bf16rne(a1 * inv) << 16);
    o.y = bf16rne(a2 * inv) | (bf16rne(a3 * inv) << 16);
    o.z = bf16rne(a4 * inv) | (bf16rne(a5 * inv) << 16);
    o.w = bf16rne(a6 * inv) | (bf16rne(a7 * inv) << 16);
    *(uint4*)(mb + (size_t)n * 256 + lnb) = o;
}

// ---------------------------------------------------------------------------
// gemm: barrier-free, LDS-free. 4 waves per 16-node tile; wave wv owns cols
// [wv*32, wv*32+32). Means from global mb, x-frags from xb, B from Bf (L2-hot).
// epilogue: out = x + relu(C + bl)
// ---------------------------------------------------------------------------
__global__ __launch_bounds__(256) void sage_mm(
    const char* __restrict__ xb, const char* __restrict__ mb,
    const uint4* __restrict__ Bf, const float* __restrict__ bl,
    const float* __restrict__ x, float* __restrict__ out, int N)
{
    const int t = threadIdx.x;
    const int nb0 = blockIdx.x * GN;
    const int wv = t >> 6;
    const int lane = t & 63;
    const int q = lane >> 4, m16 = lane & 15;
    const int am = min(nb0 + m16, N - 1);
    const short8* arow = (const short8*)(xb + (size_t)am * 256);
    const short8* mrow = (const short8*)(mb + (size_t)am * 256);
    const short8* bfp  = (const short8*)Bf;

    float4v acc[2];
    #pragma unroll
    for (int c4 = 0; c4 < 2; ++c4) acc[c4] = (float4v){0.f, 0.f, 0.f, 0.f};

    #pragma unroll
    for (int ks = 0; ks < 4; ++ks) {          // mean @ Wl
        short8 af = mrow[ks * 4 + q];
        #pragma unroll
        for (int c4 = 0; c4 < 2; ++c4) {
            int ct = wv * 2 + c4;
            short8 bfrag = bfp[(ks * 8 + ct) * 64 + lane];
            acc[c4] = __builtin_amdgcn_mfma_f32_16x16x32_bf16(af, bfrag, acc[c4], 0, 0, 0);
        }
    }
    #pragma unroll
    for (int ks = 0; ks < 4; ++ks) {          // x @ Wr
        short8 af = arow[ks * 4 + q];
        #pragma unroll
        for (int c4 = 0; c4 < 2; ++c4) {
            int ct = wv * 2 + c4;
            short8 bfrag = bfp[((ks + 4) * 8 + ct) * 64 + lane];
            acc[c4] = __builtin_amdgcn_mfma_f32_16x16x32_bf16(af, bfrag, acc[c4], 0, 0, 0);
        }
    }

    #pragma unroll
    for (int c4 = 0; c4 < 2; ++c4) {
        int col = (wv * 2 + c4) * 16 + m16;
        float b = bl[col];
        #pragma unroll
        for (int r = 0; r < 4; ++r) {
            int n2 = nb0 + q * 4 + r;
            if (n2 < N) {
                size_t idx = (size_t)n2 * DF + col;
                out[idx] = x[idx] + fmaxf(acc[c4][r] + b, 0.f);
            }
        }
    }
}

extern "C" void kernel_launch(void* const* d_in, const int* in_sizes, int n_in,
                              void* d_out, int out_size, void* d_ws, size_t ws_size,
                              hipStream_t stream) {
    const float* x  = (const float*)d_in[0];
    const int*   ei = (const int*)d_in[1];
    const float* Wl = (const float*)d_in[2];
    const float* bl = (const float*)d_in[3];
    const float* Wr = (const float*)d_in[4];
    float* out = (float*)d_out;

    const int N = in_sizes[0] / DF;
    const int E = in_sizes[1] / 2;
    const int* src = ei;
    const int* dst = ei + E;

    // ws: off[N+1] | cur[N] | srt[E] | blktot[64] | pad256 | Bf[4096*16B]
    //     | xb[N*256B] | mb[N*256B]
    int* off    = (int*)d_ws;
    int* cur    = off + (N + 1);
    int* srt    = cur + N;
    int* blktot = srt + E;
    size_t bfoff = ((size_t)(N + 1 + N + E + 64) * 4 + 255) & ~(size_t)255;
    uint4* Bf   = (uint4*)((char*)d_ws + bfoff);
    char* xb    = (char*)d_ws + bfoff + 4096 * 16;
    char* mb    = xb + (size_t)N * 256;

    hipMemsetAsync(off, 0, (size_t)(N + 1) * sizeof(int), stream);

    int prepT = N * 16;
    sage_prep<<<(prepT + 255) / 256, 256, 0, stream>>>(
        x, dst, Wl, Wr, off, xb, Bf, N, E);
    scan_reduce<<<SCAN_B, SCAN_T, 0, stream>>>(off, blktot, N);
    scan_write<<<SCAN_B, SCAN_T, 0, stream>>>(off, cur, blktot, N, E);
    sage_sort<<<(E + 255) / 256, 256, 0, stream>>>(src, dst, cur, srt, E);
    sage_gath<<<(N + GN - 1) / GN, 256, 0, stream>>>(xb, off, srt, mb, N);
    sage_mm<<<(N + GN - 1) / GN, 256, 0, stream>>>(xb, mb, Bf, bl, x, out, N);
}

// Round 4
// 198.602 us; speedup vs baseline: 1.0282x; 1.0282x over previous
//
#include <hip/hip_runtime.h>

#define DF 128
#define SCAN_B 64
#define SCAN_T 256
#define GN 16           // nodes per gather_gemm block
#define MST 272         // LDS mean-row stride bytes (17*16)

typedef __attribute__((ext_vector_type(8))) short short8;
typedef __attribute__((ext_vector_type(4))) float float4v;

__device__ __forceinline__ unsigned int bf16rne(float f) {
    unsigned int u = __float_as_uint(f);
    return (u + 0x7fffu + ((u >> 16) & 1u)) >> 16;
}

// ---------------------------------------------------------------------------
// prep: fused (a) histogram of dst, (b) x fp32->bf16 cast into compact xb
// plus int8 row-quantized xq + rowscale, (c) [Wl;Wr] swizzle into MFMA
// B-fragment order (bf16).
// ---------------------------------------------------------------------------
__global__ __launch_bounds__(256) void sage_prep(
    const float* __restrict__ x, const int* __restrict__ dst,
    const float* __restrict__ Wl, const float* __restrict__ Wr,
    int* __restrict__ cnt, char* __restrict__ xb, char* __restrict__ xq,
    float* __restrict__ rowscale, uint4* __restrict__ Bf,
    int N, int E)
{
    int tid = blockIdx.x * 256 + threadIdx.x;

    if (tid < N * 16) {                      // xcast: 16 threads/row
        int n = tid >> 4;
        int ln = tid & 15;
        int c = ln * 8;
        const float4* xp = (const float4*)&x[(size_t)n * DF + c];
        float4 a = xp[0], b = xp[1];

        // bf16 row (for MFMA A-side)
        uint4 o;
        o.x = bf16rne(a.x) | (bf16rne(a.y) << 16);
        o.y = bf16rne(a.z) | (bf16rne(a.w) << 16);
        o.z = bf16rne(b.x) | (bf16rne(b.y) << 16);
        o.w = bf16rne(b.z) | (bf16rne(b.w) << 16);
        *(uint4*)(xb + (size_t)n * 256 + (size_t)ln * 16) = o;

        // row absmax over 128 cols: local 8 then shfl_xor across 16 lanes
        float am = fmaxf(fmaxf(fmaxf(fabsf(a.x), fabsf(a.y)),
                               fmaxf(fabsf(a.z), fabsf(a.w))),
                         fmaxf(fmaxf(fabsf(b.x), fabsf(b.y)),
                               fmaxf(fabsf(b.z), fabsf(b.w))));
        #pragma unroll
        for (int s = 1; s < 16; s <<= 1) am = fmaxf(am, __shfl_xor(am, s, 16));
        float scl = am * (1.0f / 127.0f);
        float inv = (am > 0.f) ? 127.0f / am : 0.f;

        int q0 = (int)rintf(a.x * inv), q1 = (int)rintf(a.y * inv);
        int q2 = (int)rintf(a.z * inv), q3 = (int)rintf(a.w * inv);
        int q4 = (int)rintf(b.x * inv), q5 = (int)rintf(b.y * inv);
        int q6 = (int)rintf(b.z * inv), q7 = (int)rintf(b.w * inv);
        uint2 p;
        p.x = (q0 & 255) | ((q1 & 255) << 8) | ((q2 & 255) << 16) | ((unsigned)q3 << 24);
        p.y = (q4 & 255) | ((q5 & 255) << 8) | ((q6 & 255) << 16) | ((unsigned)q7 << 24);
        *(uint2*)(xq + (size_t)n * 128 + (size_t)ln * 8) = p;
        if (ln == 0) rowscale[n] = scl;
    }

    if (tid < E) atomicAdd(&cnt[dst[tid]], 1);   // histogram

    if (tid < 4096) {                        // bprep
        int lane = tid & 63;
        int ctks = tid >> 6;
        int ks = ctks >> 3, ct = ctks & 7;
        int q = lane >> 4, m16 = lane & 15;
        int n = ct * 16 + m16;
        unsigned int w[4];
        #pragma unroll
        for (int p2 = 0; p2 < 4; ++p2) {
            int k0 = ks * 32 + q * 8 + p2 * 2;
            float f0 = (k0 < DF) ? Wl[k0 * DF + n] : Wr[(k0 - DF) * DF + n];
            float f1 = (k0 + 1 < DF) ? Wl[(k0 + 1) * DF + n] : Wr[(k0 + 1 - DF) * DF + n];
            w[p2] = bf16rne(f0) | (bf16rne(f1) << 16);
        }
        uint4 o = {w[0], w[1], w[2], w[3]};
        Bf[tid] = o;
    }
}

// ---------------------------------------------------------------------------
// scan pass 1: per-block reduce -> blktot
// ---------------------------------------------------------------------------
__global__ __launch_bounds__(SCAN_T) void scan_reduce(
    const int* __restrict__ cnt, int* __restrict__ blktot, int N)
{
    __shared__ int sdata[SCAN_T];
    const int t = threadIdx.x, b = blockIdx.x;
    const int chunk = (N + SCAN_B * SCAN_T - 1) / (SCAN_B * SCAN_T);
    const int lo = (b * SCAN_T + t) * chunk;
    const int hi = min(lo + chunk, N);
    int total = 0;
    for (int i = lo; i < hi; ++i) total += cnt[i];
    sdata[t] = total;
    __syncthreads();
    for (int s = SCAN_T / 2; s > 0; s >>= 1) {
        if (t < s) sdata[t] += sdata[t + s];
        __syncthreads();
    }
    if (t == 0) blktot[b] = sdata[0];
}

// ---------------------------------------------------------------------------
// scan pass 2: block base via 64 parallel loads + LDS scan + write
// ---------------------------------------------------------------------------
__global__ __launch_bounds__(SCAN_T) void scan_write(
    int* __restrict__ off, int* __restrict__ cur,
    const int* __restrict__ blktot, int N, int E)
{
    __shared__ int sdata[SCAN_T];
    __shared__ int sbl[64];
    __shared__ int sbase;
    const int t = threadIdx.x, b = blockIdx.x;
    const int chunk = (N + SCAN_B * SCAN_T - 1) / (SCAN_B * SCAN_T);
    const int lo = (b * SCAN_T + t) * chunk;
    const int hi = min(lo + chunk, N);

    if (t < 64) sbl[t] = (t < b) ? blktot[t] : 0;
    int total = 0;
    for (int i = lo; i < hi; ++i) total += off[i];
    sdata[t] = total;
    __syncthreads();
    if (t == 0) {
        int s = 0;
        #pragma unroll
        for (int i = 0; i < 64; ++i) s += sbl[i];
        sbase = s;
    }
    for (int s = 1; s < SCAN_T; s <<= 1) {
        int v = (t >= s) ? sdata[t - s] : 0;
        __syncthreads();
        sdata[t] += v;
        __syncthreads();
    }
    int running = sbase + ((t > 0) ? sdata[t - 1] : 0);
    for (int i = lo; i < hi; ++i) {
        int c = off[i];
        off[i] = running;
        cur[i] = running;
        running += c;
    }
    if (b == 0 && t == 0) off[N] = E;
}

// ---------------------------------------------------------------------------
// counting-sort of src by dst bucket
// ---------------------------------------------------------------------------
__global__ __launch_bounds__(256) void sage_sort(
    const int* __restrict__ src, const int* __restrict__ dst,
    int* __restrict__ cur, int* __restrict__ srt, int E)
{
    int e = blockIdx.x * 256 + threadIdx.x;
    if (e < E) {
        int p = atomicAdd(&cur[dst[e]], 1);
        srt[p] = src[e];
    }
}

// ---------------------------------------------------------------------------
// fused gather + gemm, GN=16 nodes/block:
//   phase 1: 16 lanes/node; lane owns 8B (8 int8 cols) of the 128B xq row;
//            16 rows of loads in flight (uint2 + rowscale broadcast);
//            a[c] += scale_s * q ; means -> LDS bf16.
//   phase 2: 4 waves; wave wv owns cols [wv*32, wv*32+32) of all 16 rows.
//   epilogue: out = x + relu(C + bl)
// ---------------------------------------------------------------------------
__device__ __forceinline__ void unp8(uint2 w, float sc, float* a) {
    a[0] += sc * (float)((int)(w.x << 24) >> 24);
    a[1] += sc * (float)((int)(w.x << 16) >> 24);
    a[2] += sc * (float)((int)(w.x <<  8) >> 24);
    a[3] += sc * (float)((int)(w.x      ) >> 24);
    a[4] += sc * (float)((int)(w.y << 24) >> 24);
    a[5] += sc * (float)((int)(w.y << 16) >> 24);
    a[6] += sc * (float)((int)(w.y <<  8) >> 24);
    a[7] += sc * (float)((int)(w.y      ) >> 24);
}

__global__ __launch_bounds__(256) void sage_gg(
    const char* __restrict__ xq, const float* __restrict__ rowscale,
    const char* __restrict__ xb, const int* __restrict__ off,
    const int* __restrict__ srt, const uint4* __restrict__ Bf,
    const float* __restrict__ bl, const float* __restrict__ x,
    float* __restrict__ out, int N)
{
    __shared__ char mlds[GN * MST];
    const int t = threadIdx.x;
    const int nb0 = blockIdx.x * GN;

    // ---- phase 1: int8 gather-mean ----
    {
        const int ln = t & 15;
        const int g  = t >> 4;
        const int n = nb0 + g;
        const uint2* xq2 = (const uint2*)xq;

        float a[8];
        #pragma unroll
        for (int k = 0; k < 8; ++k) a[k] = 0.f;
        int deg = 1;

        if (n < N) {
            const int start = off[n];
            const int end   = off[n + 1];
            deg = max(end - start, 1);

            int sv = 0;
            if (start + ln < end) sv = srt[start + ln];

            for (int e0 = start; e0 < end; e0 += 16) {
                int svn = 0;
                if (e0 + 16 + ln < end) svn = srt[e0 + 16 + ln];
                const int m = end - e0;      // group-uniform

                uint2 v[16];
                float sc[16];
                #pragma unroll
                for (int j = 0; j < 16; ++j) {
                    if (j < m) {
                        int s = __shfl(sv, j, 16);
                        v[j]  = xq2[(size_t)s * 16 + ln];
                        sc[j] = rowscale[s];
                    }
                }
                #pragma unroll
                for (int j = 0; j < 16; ++j) {
                    if (j < m) unp8(v[j], sc[j], a);
                }
                sv = svn;
            }
        }

        float inv = 1.0f / (float)deg;
        uint4 o;
        o.x = bf16rne(a[0] * inv) | (bf16rne(a[1] * inv) << 16);
        o.y = bf16rne(a[2] * inv) | (bf16rne(a[3] * inv) << 16);
        o.z = bf16rne(a[4] * inv) | (bf16rne(a[5] * inv) << 16);
        o.w = bf16rne(a[6] * inv) | (bf16rne(a[7] * inv) << 16);
        *(uint4*)(mlds + g * MST + ln * 16) = o;
    }
    __syncthreads();

    // ---- phase 2: MFMA; wave wv owns a 32-col slice of all 16 rows ----
    const int wv = t >> 6;
    const int lane = t & 63;
    const int q = lane >> 4, m16 = lane & 15;
    const int am = min(nb0 + m16, N - 1);
    const short8* arow = (const short8*)(xb + (size_t)am * 256);
    const short8* mrow = (const short8*)(mlds + m16 * MST);
    const short8* bfp  = (const short8*)Bf;

    float4v acc[2];
    #pragma unroll
    for (int c4 = 0; c4 < 2; ++c4) acc[c4] = (float4v){0.f, 0.f, 0.f, 0.f};

    #pragma unroll
    for (int ks = 0; ks < 4; ++ks) {          // mean @ Wl
        short8 af = mrow[ks * 4 + q];
        #pragma unroll
        for (int c4 = 0; c4 < 2; ++c4) {
            int ct = wv * 2 + c4;
            short8 bfrag = bfp[(ks * 8 + ct) * 64 + lane];
            acc[c4] = __builtin_amdgcn_mfma_f32_16x16x32_bf16(af, bfrag, acc[c4], 0, 0, 0);
        }
    }
    #pragma unroll
    for (int ks = 0; ks < 4; ++ks) {          // x @ Wr
        short8 af = arow[ks * 4 + q];
        #pragma unroll
        for (int c4 = 0; c4 < 2; ++c4) {
            int ct = wv * 2 + c4;
            short8 bfrag = bfp[((ks + 4) * 8 + ct) * 64 + lane];
            acc[c4] = __builtin_amdgcn_mfma_f32_16x16x32_bf16(af, bfrag, acc[c4], 0, 0, 0);
        }
    }

    // ---- epilogue ----
    #pragma unroll
    for (int c4 = 0; c4 < 2; ++c4) {
        int col = (wv * 2 + c4) * 16 + m16;
        float b = bl[col];
        #pragma unroll
        for (int r = 0; r < 4; ++r) {
            int n2 = nb0 + q * 4 + r;
            if (n2 < N) {
                size_t idx = (size_t)n2 * DF + col;
                out[idx] = x[idx] + fmaxf(acc[c4][r] + b, 0.f);
            }
        }
    }
}

extern "C" void kernel_launch(void* const* d_in, const int* in_sizes, int n_in,
                              void* d_out, int out_size, void* d_ws, size_t ws_size,
                              hipStream_t stream) {
    const float* x  = (const float*)d_in[0];
    const int*   ei = (const int*)d_in[1];
    const float* Wl = (const float*)d_in[2];
    const float* bl = (const float*)d_in[3];
    const float* Wr = (const float*)d_in[4];
    float* out = (float*)d_out;

    const int N = in_sizes[0] / DF;
    const int E = in_sizes[1] / 2;
    const int* src = ei;
    const int* dst = ei + E;

    // ws: off[N+1] | cur[N] | srt[E] | blktot[64] | pad256 | Bf[4096*16B]
    //     | xb[N*256B] | xq[N*128B] | rowscale[N*4B]
    int* off    = (int*)d_ws;
    int* cur    = off + (N + 1);
    int* srt    = cur + N;
    int* blktot = srt + E;
    size_t bfoff = ((size_t)(N + 1 + N + E + 64) * 4 + 255) & ~(size_t)255;
    uint4* Bf   = (uint4*)((char*)d_ws + bfoff);
    char* xb    = (char*)d_ws + bfoff + 4096 * 16;
    char* xq    = xb + (size_t)N * 256;
    float* rowscale = (float*)(xq + (size_t)N * 128);

    hipMemsetAsync(off, 0, (size_t)(N + 1) * sizeof(int), stream);

    int prepT = N * 16;
    sage_prep<<<(prepT + 255) / 256, 256, 0, stream>>>(
        x, dst, Wl, Wr, off, xb, xq, rowscale, Bf, N, E);
    scan_reduce<<<SCAN_B, SCAN_T, 0, stream>>>(off, blktot, N);
    scan_write<<<SCAN_B, SCAN_T, 0, stream>>>(off, cur, blktot, N, E);
    sage_sort<<<(E + 255) / 256, 256, 0, stream>>>(src, dst, cur, srt, E);
    sage_gg<<<(N + GN - 1) / GN, 256, 0, stream>>>(
        xq, rowscale, xb, off, srt, Bf, bl, x, out, N);
}

// Round 6
// 185.332 us; speedup vs baseline: 1.1018x; 1.0716x over previous
//
#include <hip/hip_runtime.h>

#define DF 128
#define SCAN_B 64
#define SCAN_T 256
#define GN 16           // nodes per gather_gemm block
#define MST 272         // LDS mean-row stride bytes (17*16)

typedef __attribute__((ext_vector_type(8))) short short8;
typedef __attribute__((ext_vector_type(4))) float float4v;

__device__ __forceinline__ unsigned int bf16rne(float f) {
    unsigned int u = __float_as_uint(f);
    return (u + 0x7fffu + ((u >> 16) & 1u)) >> 16;
}

// ---------------------------------------------------------------------------
// prep: fused (a) histogram of dst, (b) x fp32->bf16 cast into compact xb
// plus int8 row-quantized xq + rowscale, (c) [Wl;Wr] swizzle into MFMA
// B-fragment order (bf16).
// ---------------------------------------------------------------------------
__global__ __launch_bounds__(256) void sage_prep(
    const float* __restrict__ x, const int* __restrict__ dst,
    const float* __restrict__ Wl, const float* __restrict__ Wr,
    int* __restrict__ cnt, char* __restrict__ xb, char* __restrict__ xq,
    float* __restrict__ rowscale, uint4* __restrict__ Bf,
    int N, int E)
{
    int tid = blockIdx.x * 256 + threadIdx.x;

    if (tid < N * 16) {                      // xcast: 16 threads/row
        int n = tid >> 4;
        int ln = tid & 15;
        int c = ln * 8;
        const float4* xp = (const float4*)&x[(size_t)n * DF + c];
        float4 a = xp[0], b = xp[1];

        // bf16 row (for MFMA A-side)
        uint4 o;
        o.x = bf16rne(a.x) | (bf16rne(a.y) << 16);
        o.y = bf16rne(a.z) | (bf16rne(a.w) << 16);
        o.z = bf16rne(b.x) | (bf16rne(b.y) << 16);
        o.w = bf16rne(b.z) | (bf16rne(b.w) << 16);
        *(uint4*)(xb + (size_t)n * 256 + (size_t)ln * 16) = o;

        // row absmax over 128 cols: local 8 then shfl_xor across 16 lanes
        float am = fmaxf(fmaxf(fmaxf(fabsf(a.x), fabsf(a.y)),
                               fmaxf(fabsf(a.z), fabsf(a.w))),
                         fmaxf(fmaxf(fabsf(b.x), fabsf(b.y)),
                               fmaxf(fabsf(b.z), fabsf(b.w))));
        #pragma unroll
        for (int s = 1; s < 16; s <<= 1) am = fmaxf(am, __shfl_xor(am, s, 16));
        float scl = am * (1.0f / 127.0f);
        float inv = (am > 0.f) ? 127.0f / am : 0.f;

        int q0 = (int)rintf(a.x * inv), q1 = (int)rintf(a.y * inv);
        int q2 = (int)rintf(a.z * inv), q3 = (int)rintf(a.w * inv);
        int q4 = (int)rintf(b.x * inv), q5 = (int)rintf(b.y * inv);
        int q6 = (int)rintf(b.z * inv), q7 = (int)rintf(b.w * inv);
        uint2 p;
        p.x = (q0 & 255) | ((q1 & 255) << 8) | ((q2 & 255) << 16) | ((unsigned)q3 << 24);
        p.y = (q4 & 255) | ((q5 & 255) << 8) | ((q6 & 255) << 16) | ((unsigned)q7 << 24);
        *(uint2*)(xq + (size_t)n * 128 + (size_t)ln * 8) = p;
        if (ln == 0) rowscale[n] = scl;
    }

    if (tid < E) atomicAdd(&cnt[dst[tid]], 1);   // histogram

    if (tid < 4096) {                        // bprep
        int lane = tid & 63;
        int ctks = tid >> 6;
        int ks = ctks >> 3, ct = ctks & 7;
        int q = lane >> 4, m16 = lane & 15;
        int n = ct * 16 + m16;
        unsigned int w[4];
        #pragma unroll
        for (int p2 = 0; p2 < 4; ++p2) {
            int k0 = ks * 32 + q * 8 + p2 * 2;
            float f0 = (k0 < DF) ? Wl[k0 * DF + n] : Wr[(k0 - DF) * DF + n];
            float f1 = (k0 + 1 < DF) ? Wl[(k0 + 1) * DF + n] : Wr[(k0 + 1 - DF) * DF + n];
            w[p2] = bf16rne(f0) | (bf16rne(f1) << 16);
        }
        uint4 o = {w[0], w[1], w[2], w[3]};
        Bf[tid] = o;
    }
}

// ---------------------------------------------------------------------------
// scan pass 1: per-block reduce -> blktot
// ---------------------------------------------------------------------------
__global__ __launch_bounds__(SCAN_T) void scan_reduce(
    const int* __restrict__ cnt, int* __restrict__ blktot, int N)
{
    __shared__ int sdata[SCAN_T];
    const int t = threadIdx.x, b = blockIdx.x;
    const int chunk = (N + SCAN_B * SCAN_T - 1) / (SCAN_B * SCAN_T);
    const int lo = (b * SCAN_T + t) * chunk;
    const int hi = min(lo + chunk, N);
    int total = 0;
    for (int i = lo; i < hi; ++i) total += cnt[i];
    sdata[t] = total;
    __syncthreads();
    for (int s = SCAN_T / 2; s > 0; s >>= 1) {
        if (t < s) sdata[t] += sdata[t + s];
        __syncthreads();
    }
    if (t == 0) blktot[b] = sdata[0];
}

// ---------------------------------------------------------------------------
// scan pass 2: block base via 64 parallel loads + LDS scan + write
// ---------------------------------------------------------------------------
__global__ __launch_bounds__(SCAN_T) void scan_write(
    int* __restrict__ off, int* __restrict__ cur,
    const int* __restrict__ blktot, int N, int E)
{
    __shared__ int sdata[SCAN_T];
    __shared__ int sbl[64];
    __shared__ int sbase;
    const int t = threadIdx.x, b = blockIdx.x;
    const int chunk = (N + SCAN_B * SCAN_T - 1) / (SCAN_B * SCAN_T);
    const int lo = (b * SCAN_T + t) * chunk;
    const int hi = min(lo + chunk, N);

    if (t < 64) sbl[t] = (t < b) ? blktot[t] : 0;
    int total = 0;
    for (int i = lo; i < hi; ++i) total += off[i];
    sdata[t] = total;
    __syncthreads();
    if (t == 0) {
        int s = 0;
        #pragma unroll
        for (int i = 0; i < 64; ++i) s += sbl[i];
        sbase = s;
    }
    for (int s = 1; s < SCAN_T; s <<= 1) {
        int v = (t >= s) ? sdata[t - s] : 0;
        __syncthreads();
        sdata[t] += v;
        __syncthreads();
    }
    int running = sbase + ((t > 0) ? sdata[t - 1] : 0);
    for (int i = lo; i < hi; ++i) {
        int c = off[i];
        off[i] = running;
        cur[i] = running;
        running += c;
    }
    if (b == 0 && t == 0) off[N] = E;
}

// ---------------------------------------------------------------------------
// counting-sort of src by dst bucket
// ---------------------------------------------------------------------------
__global__ __launch_bounds__(256) void sage_sort(
    const int* __restrict__ src, const int* __restrict__ dst,
    int* __restrict__ cur, int* __restrict__ srt, int E)
{
    int e = blockIdx.x * 256 + threadIdx.x;
    if (e < E) {
        int p = atomicAdd(&cur[dst[e]], 1);
        srt[p] = src[e];
    }
}

// ---------------------------------------------------------------------------
// fused gather + gemm, GN=16 nodes/block:
//   phase 1 (pair-edge): 16 lanes/node; lanes 0-7 load edge 2j's 128B int8
//            row as 8 x uint4, lanes 8-15 load edge 2j+1's -> one instruction
//            covers TWO edges. rowscale prefetched once per 16-edge batch and
//            shfl-broadcast. NOTE: shfl must be OUTSIDE the lane-dependent
//            predicate (inactive bpermute sources return undefined data);
//            only the load/unpack are guarded. Lane accumulates 16 cols;
//            cross-half shfl_xor(8) reduce; means -> LDS bf16.
//   phase 2: 4 waves; wave wv owns cols [wv*32, wv*32+32) of all 16 rows.
//   epilogue: out = x + relu(C + bl)
// ---------------------------------------------------------------------------
__device__ __forceinline__ void unp16(uint4 w, float sc, float* a) {
    a[ 0] += sc * (float)((int)(w.x << 24) >> 24);
    a[ 1] += sc * (float)((int)(w.x << 16) >> 24);
    a[ 2] += sc * (float)((int)(w.x <<  8) >> 24);
    a[ 3] += sc * (float)((int)(w.x      ) >> 24);
    a[ 4] += sc * (float)((int)(w.y << 24) >> 24);
    a[ 5] += sc * (float)((int)(w.y << 16) >> 24);
    a[ 6] += sc * (float)((int)(w.y <<  8) >> 24);
    a[ 7] += sc * (float)((int)(w.y      ) >> 24);
    a[ 8] += sc * (float)((int)(w.z << 24) >> 24);
    a[ 9] += sc * (float)((int)(w.z << 16) >> 24);
    a[10] += sc * (float)((int)(w.z <<  8) >> 24);
    a[11] += sc * (float)((int)(w.z      ) >> 24);
    a[12] += sc * (float)((int)(w.w << 24) >> 24);
    a[13] += sc * (float)((int)(w.w << 16) >> 24);
    a[14] += sc * (float)((int)(w.w <<  8) >> 24);
    a[15] += sc * (float)((int)(w.w      ) >> 24);
}

__global__ __launch_bounds__(256) void sage_gg(
    const char* __restrict__ xq, const float* __restrict__ rowscale,
    const char* __restrict__ xb, const int* __restrict__ off,
    const int* __restrict__ srt, const uint4* __restrict__ Bf,
    const float* __restrict__ bl, const float* __restrict__ x,
    float* __restrict__ out, int N)
{
    __shared__ char mlds[GN * MST];
    const int t = threadIdx.x;
    const int nb0 = blockIdx.x * GN;

    // ---- phase 1: pair-edge int8 gather-mean ----
    {
        const int ln = t & 15;
        const int g  = t >> 4;
        const int h  = ln >> 3;          // 0: even edge of pair, 1: odd
        const int l8 = ln & 7;
        const int n = nb0 + g;
        const uint4* xq4 = (const uint4*)xq;   // 8 uint4 per 128B row

        float a[16];
        #pragma unroll
        for (int k = 0; k < 16; ++k) a[k] = 0.f;
        int deg = 1;

        if (n < N) {
            const int start = off[n];
            const int end   = off[n + 1];
            deg = max(end - start, 1);

            int sv = 0; float scv = 0.f;
            if (start + ln < end) {
                sv  = srt[start + ln];
                scv = rowscale[sv];
            }

            for (int e0 = start; e0 < end; e0 += 16) {
                int svn = 0; float scvn = 0.f;
                if (e0 + 16 + ln < end) {
                    svn  = srt[e0 + 16 + ln];
                    scvn = rowscale[svn];
                }
                const int m = end - e0;      // group-uniform

                uint4 v[8];
                float sc[8];
                #pragma unroll
                for (int j = 0; j < 8; ++j) {
                    // shfl with ALL lanes active (uniform), then guarded load
                    int   s = __shfl(sv,  2 * j + h, 16);
                    sc[j]   = __shfl(scv, 2 * j + h, 16);
                    if (2 * j + h < m) {
                        v[j] = xq4[(size_t)s * 8 + l8];
                    }
                }
                #pragma unroll
                for (int j = 0; j < 8; ++j) {
                    if (2 * j + h < m) unp16(v[j], sc[j], a);
                }
                sv = svn; scv = scvn;
            }
        }

        // cross-half reduce: lane ln and ln^8 hold same cols, different edges
        #pragma unroll
        for (int k = 0; k < 16; ++k) a[k] += __shfl_xor(a[k], 8, 16);

        // lane writes its half's 8 cols: cols l8*16 + h*8 .. +8
        float inv = 1.0f / (float)deg;
        float b0 = h ? a[ 8] : a[ 0];
        float b1 = h ? a[ 9] : a[ 1];
        float b2 = h ? a[10] : a[ 2];
        float b3 = h ? a[11] : a[ 3];
        float b4 = h ? a[12] : a[ 4];
        float b5 = h ? a[13] : a[ 5];
        float b6 = h ? a[14] : a[ 6];
        float b7 = h ? a[15] : a[ 7];
        uint4 o;
        o.x = bf16rne(b0 * inv) | (bf16rne(b1 * inv) << 16);
        o.y = bf16rne(b2 * inv) | (bf16rne(b3 * inv) << 16);
        o.z = bf16rne(b4 * inv) | (bf16rne(b5 * inv) << 16);
        o.w = bf16rne(b6 * inv) | (bf16rne(b7 * inv) << 16);
        *(uint4*)(mlds + g * MST + l8 * 32 + h * 16) = o;
    }
    __syncthreads();

    // ---- phase 2: MFMA; wave wv owns a 32-col slice of all 16 rows ----
    const int wv = t >> 6;
    const int lane = t & 63;
    const int q = lane >> 4, m16 = lane & 15;
    const int am = min(nb0 + m16, N - 1);
    const short8* arow = (const short8*)(xb + (size_t)am * 256);
    const short8* mrow = (const short8*)(mlds + m16 * MST);
    const short8* bfp  = (const short8*)Bf;

    float4v acc[2];
    #pragma unroll
    for (int c4 = 0; c4 < 2; ++c4) acc[c4] = (float4v){0.f, 0.f, 0.f, 0.f};

    #pragma unroll
    for (int ks = 0; ks < 4; ++ks) {          // mean @ Wl
        short8 af = mrow[ks * 4 + q];
        #pragma unroll
        for (int c4 = 0; c4 < 2; ++c4) {
            int ct = wv * 2 + c4;
            short8 bfrag = bfp[(ks * 8 + ct) * 64 + lane];
            acc[c4] = __builtin_amdgcn_mfma_f32_16x16x32_bf16(af, bfrag, acc[c4], 0, 0, 0);
        }
    }
    #pragma unroll
    for (int ks = 0; ks < 4; ++ks) {          // x @ Wr
        short8 af = arow[ks * 4 + q];
        #pragma unroll
        for (int c4 = 0; c4 < 2; ++c4) {
            int ct = wv * 2 + c4;
            short8 bfrag = bfp[((ks + 4) * 8 + ct) * 64 + lane];
            acc[c4] = __builtin_amdgcn_mfma_f32_16x16x32_bf16(af, bfrag, acc[c4], 0, 0, 0);
        }
    }

    // ---- epilogue ----
    #pragma unroll
    for (int c4 = 0; c4 < 2; ++c4) {
        int col = (wv * 2 + c4) * 16 + m16;
        float b = bl[col];
        #pragma unroll
        for (int r = 0; r < 4; ++r) {
            int n2 = nb0 + q * 4 + r;
            if (n2 < N) {
                size_t idx = (size_t)n2 * DF + col;
                out[idx] = x[idx] + fmaxf(acc[c4][r] + b, 0.f);
            }
        }
    }
}

extern "C" void kernel_launch(void* const* d_in, const int* in_sizes, int n_in,
                              void* d_out, int out_size, void* d_ws, size_t ws_size,
                              hipStream_t stream) {
    const float* x  = (const float*)d_in[0];
    const int*   ei = (const int*)d_in[1];
    const float* Wl = (const float*)d_in[2];
    const float* bl = (const float*)d_in[3];
    const float* Wr = (const float*)d_in[4];
    float* out = (float*)d_out;

    const int N = in_sizes[0] / DF;
    const int E = in_sizes[1] / 2;
    const int* src = ei;
    const int* dst = ei + E;

    // ws: off[N+1] | cur[N] | srt[E] | blktot[64] | pad256 | Bf[4096*16B]
    //     | xb[N*256B] | xq[N*128B] | rowscale[N*4B]
    int* off    = (int*)d_ws;
    int* cur    = off + (N + 1);
    int* srt    = cur + N;
    int* blktot = srt + E;
    size_t bfoff = ((size_t)(N + 1 + N + E + 64) * 4 + 255) & ~(size_t)255;
    uint4* Bf   = (uint4*)((char*)d_ws + bfoff);
    char* xb    = (char*)d_ws + bfoff + 4096 * 16;
    char* xq    = xb + (size_t)N * 256;
    float* rowscale = (float*)(xq + (size_t)N * 128);

    hipMemsetAsync(off, 0, (size_t)(N + 1) * sizeof(int), stream);

    int prepT = N * 16;
    sage_prep<<<(prepT + 255) / 256, 256, 0, stream>>>(
        x, dst, Wl, Wr, off, xb, xq, rowscale, Bf, N, E);
    scan_reduce<<<SCAN_B, SCAN_T, 0, stream>>>(off, blktot, N);
    scan_write<<<SCAN_B, SCAN_T, 0, stream>>>(off, cur, blktot, N, E);
    sage_sort<<<(E + 255) / 256, 256, 0, stream>>>(src, dst, cur, srt, E);
    sage_gg<<<(N + GN - 1) / GN, 256, 0, stream>>>(
        xq, rowscale, xb, off, srt, Bf, bl, x, out, N);
}